// Round 5
// baseline (17995.287 us; speedup 1.0000x reference)
//
#include <hip/hip_runtime.h>
#include <hip/hip_bf16.h>
#include <stdint.h>

// GRU decoder: B=128, IN=256, H=512, SEQ=1024. OUTPUT IS FP32 (reference
// returns fp32; R0-R4 bisection showed the recurrence was correct all along
// and only the out dtype was wrong).
// 8 batch-groups x 16 hidden-groups = 128 one-wave workgroups.
// Each WG: 16 batch rows x 32 hidden cols (x3 gates = 96 w_hh rows).
// w_hh bf16 slice L2-resident; h fp32 in registers, exchanged as bf16 via
// system-scope atomics + per-batch-group counter barrier.

constexpr int SEQ = 1024;
constexpr int BATCH = 128;
constexpr int IND = 256;
constexpr int HD = 512;
constexpr int BG = 8;
constexpr int HG = 16;
constexpr int ROWS = BATCH / BG;   // 16
constexpr int NT = 6;              // tiles: r0 r1 z0 z1 n0 n1 (16 cols each)

using frag16 = __attribute__((ext_vector_type(8))) short;  // 8 bf16
using f32x4  = __attribute__((ext_vector_type(4))) float;

constexpr size_t WS_WHH  = 0;                                    // 1536*512 bf16
constexpr size_t WS_HBUF = (size_t)3 * HD * HD * 2;              // 2*B*H bf16
constexpr size_t WS_CNT  = WS_HBUF + (size_t)2 * BATCH * HD * 2; // BG*SEQ u32

struct alignas(8) bf4 { __hip_bfloat16 x, y, z, w; };

__global__ void cvt_w_kernel(const float4* __restrict__ src, bf4* __restrict__ dst) {
    int i = blockIdx.x * blockDim.x + threadIdx.x;  // 196608 float4s
    float4 v = src[i];
    bf4 o;
    o.x = __float2bfloat16(v.x);
    o.y = __float2bfloat16(v.y);
    o.z = __float2bfloat16(v.z);
    o.w = __float2bfloat16(v.w);
    dst[i] = o;
}

__device__ __forceinline__ float sigmoid_f(float x) {
    return 1.f / (1.f + __expf(-x));
}
__device__ __forceinline__ float tanh_f(float x) {
    float e = __expf(2.f * x);
    return 1.f - 2.f / (e + 1.f);
}

__global__ __launch_bounds__(64) void gru_kernel(
    const float* __restrict__ x,
    const float* __restrict__ w_ih,
    const float* __restrict__ b_ih,
    const float* __restrict__ b_hh,
    const __hip_bfloat16* __restrict__ whh,  // [1536, 512] bf16
    unsigned* __restrict__ hbuf_u32,         // 2 * [128, 512] bf16, dword-addressed
    unsigned* __restrict__ cnt,              // [BG, SEQ]
    float* __restrict__ out)                 // [128, 1024, 512] FP32
{
    const int lane = threadIdx.x;
    const int bg = blockIdx.x & 7;
    const int hg = blockIdx.x >> 3;
    const int b0 = bg * ROWS;
    const int c0 = hg * 32;
    const int nlo = lane & 15;
    const int quad = lane >> 4;

    int gcol[NT];
    gcol[0] = c0 + nlo;            gcol[1] = c0 + 16 + nlo;
    gcol[2] = HD + c0 + nlo;       gcol[3] = HD + c0 + 16 + nlo;
    gcol[4] = 2*HD + c0 + nlo;     gcol[5] = 2*HD + c0 + 16 + nlo;

    // ---- gi = x @ w_ih.T + b_ih (+ b_hh folded for r,z) ----
    float gi[NT][4];
    float bhn[2];
#pragma unroll
    for (int t = 0; t < NT; ++t) {
        float bi = b_ih[gcol[t]] + ((t < 4) ? b_hh[gcol[t]] : 0.f);
#pragma unroll
        for (int r = 0; r < 4; ++r) gi[t][r] = bi;
    }
    bhn[0] = b_hh[gcol[4]];
    bhn[1] = b_hh[gcol[5]];

    for (int r = 0; r < 4; ++r) {
        const float4* xr = (const float4*)(x + (uint64_t)(b0 + quad*4 + r) * IND);
        for (int kc = 0; kc < IND/4; ++kc) {
            float4 xv = xr[kc];
#pragma unroll
            for (int t = 0; t < NT; ++t) {
                float4 wv = ((const float4*)(w_ih + (uint64_t)gcol[t] * IND))[kc];
                gi[t][r] += xv.x*wv.x + xv.y*wv.y + xv.z*wv.z + xv.w*wv.w;
            }
        }
    }

    // ---- recurrence ----
    const int HWORDS = BATCH * HD / 2;  // dwords per h buffer
    const uint64_t a_dw = ((uint64_t)(b0 + nlo) * HD + quad * 8) >> 1;
    uint64_t wrow[NT];
#pragma unroll
    for (int t = 0; t < NT; ++t) wrow[t] = (uint64_t)gcol[t] * HD + quad * 8;

    float hreg[2][4];
#pragma unroll
    for (int hf = 0; hf < 2; ++hf)
#pragma unroll
        for (int r = 0; r < 4; ++r) hreg[hf][r] = 0.f;

    const bool even_lane = ((lane & 1) == 0);

    for (int s = 0; s < SEQ; ++s) {
        f32x4 C[NT];
#pragma unroll
        for (int t = 0; t < NT; ++t) C[t] = (f32x4){0.f, 0.f, 0.f, 0.f};

        if (s > 0) {
            unsigned long long* hb =
                (unsigned long long*)(hbuf_u32 + (s & 1) * HWORDS);
#pragma unroll
            for (int kc = 0; kc < 16; ++kc) {
                unsigned long long* p = hb + ((a_dw + kc * 16) >> 1);
                union { unsigned long long u[2]; frag16 f; } af;
                af.u[0] = __hip_atomic_load(p,     __ATOMIC_RELAXED, __HIP_MEMORY_SCOPE_SYSTEM);
                af.u[1] = __hip_atomic_load(p + 1, __ATOMIC_RELAXED, __HIP_MEMORY_SCOPE_SYSTEM);
#pragma unroll
                for (int t = 0; t < NT; ++t) {
                    frag16 bfr = *(const frag16*)(whh + wrow[t] + kc * 32);
                    C[t] = __builtin_amdgcn_mfma_f32_16x16x32_bf16(af.f, bfr, C[t], 0, 0, 0);
                }
            }
        }

        unsigned* hw = hbuf_u32 + ((s + 1) & 1) * HWORDS;
#pragma unroll
        for (int r = 0; r < 4; ++r) {
#pragma unroll
            for (int hf = 0; hf < 2; ++hf) {
                float gr  = gi[hf][r]   + C[hf][r];
                float gz  = gi[2+hf][r] + C[2+hf][r];
                float ghn = C[4+hf][r] + bhn[hf];
                float rr = sigmoid_f(gr);
                float zz = sigmoid_f(gz);
                float nn = tanh_f(gi[4+hf][r] + rr * ghn);
                float hn = (1.f - zz) * nn + zz * hreg[hf][r];
                hreg[hf][r] = hn;
                int row = b0 + quad*4 + r;
                int col = c0 + hf*16 + nlo;
                // FP32 output store
                out[(uint64_t)row * (SEQ * HD) + (uint64_t)s * HD + col] = hn;
                // bf16 h exchange: pack (col_even, col_odd) across adjacent lanes
                __hip_bfloat16 hv = __float2bfloat16(hn);
                unsigned own = (unsigned)__bfloat16_as_ushort(hv);
                unsigned other = (unsigned)__shfl_xor((int)own, 1);
                if (even_lane) {
                    unsigned dw = own | (other << 16);
                    __hip_atomic_store(hw + ((unsigned)(row * HD + col) >> 1), dw,
                                       __ATOMIC_RELAXED, __HIP_MEMORY_SCOPE_SYSTEM);
                }
            }
        }

        if (s < SEQ - 1) {
            unsigned* c = &cnt[bg * SEQ + s];
            __threadfence_system();
            if (lane == 0)
                __hip_atomic_fetch_add(c, 1u, __ATOMIC_RELEASE, __HIP_MEMORY_SCOPE_SYSTEM);
            while (__hip_atomic_load(c, __ATOMIC_ACQUIRE, __HIP_MEMORY_SCOPE_SYSTEM) < (unsigned)HG)
                __builtin_amdgcn_s_sleep(1);
        }
    }
}

extern "C" void kernel_launch(void* const* d_in, const int* in_sizes, int n_in,
                              void* d_out, int out_size, void* d_ws, size_t ws_size,
                              hipStream_t stream) {
    (void)in_sizes; (void)n_in; (void)out_size; (void)ws_size;
    const float* x    = (const float*)d_in[0];
    const float* w_ih = (const float*)d_in[1];
    const float* w_hh = (const float*)d_in[2];
    const float* b_ih = (const float*)d_in[3];
    const float* b_hh = (const float*)d_in[4];

    char* ws = (char*)d_ws;
    __hip_bfloat16* whh_bf = (__hip_bfloat16*)(ws + WS_WHH);
    unsigned*       hbuf   = (unsigned*)(ws + WS_HBUF);
    unsigned*       cnt    = (unsigned*)(ws + WS_CNT);

    hipMemsetAsync(cnt, 0, (size_t)BG * SEQ * sizeof(unsigned), stream);
    cvt_w_kernel<<<768, 256, 0, stream>>>((const float4*)w_hh, (bf4*)whh_bf);
    gru_kernel<<<BG * HG, 64, 0, stream>>>(x, w_ih, b_ih, b_hh, whh_bf, hbuf, cnt,
                                           (float*)d_out);
}

// Round 6
// 3358.370 us; speedup vs baseline: 5.3583x; 5.3583x over previous
//
#include <hip/hip_runtime.h>
#include <hip/hip_bf16.h>
#include <stdint.h>

// GRU decoder: B=128, IN=256, H=512, SEQ=1024, fp32 out.
// R6: 8 batch-groups x 32 hidden-groups = 256 one-wave WGs (16 rows x 16 cols).
// w_hh slice (48 rows) converted to bf16 ONCE into LDS in MFMA-fragment order
// (conflict-free ds_read_b128, immune to cache maintenance). h exchanged as
// bf16 via cache-bypassing relaxed system-scope atomics; per-step sync via
// per-WG flag stores + relaxed flag polls (NO acquire-inv, NO wbl2, NO RMW
// contention). Ordering: s_waitcnt vmcnt(0) before flag store; coherence-point
// causality makes the data visible to any WG that observes the flag.

constexpr int SEQ = 1024;
constexpr int BATCH = 128;
constexpr int IND = 256;
constexpr int HD = 512;
constexpr int BG = 8;
constexpr int HG = 32;
constexpr int ROWS = BATCH / BG;   // 16
constexpr int NT = 3;              // tiles: r, z, n (16 cols each)

using frag16 = __attribute__((ext_vector_type(8))) short;  // 8 bf16
using f32x4  = __attribute__((ext_vector_type(4))) float;

constexpr size_t WS_HBUF  = 0;                        // 2*128*512 bf16 = 256 KB
constexpr size_t WS_FLAGS = (size_t)2 * BATCH * HD * 2;  // BG*HG u32

__device__ __forceinline__ float sigmoid_f(float x) {
    return 1.f / (1.f + __expf(-x));
}
__device__ __forceinline__ float tanh_f(float x) {
    float e = __expf(2.f * x);
    return 1.f - 2.f / (e + 1.f);
}
__device__ __forceinline__ short f2bf(float x) {
    return (short)__bfloat16_as_ushort(__float2bfloat16(x));
}

__global__ __launch_bounds__(64) void gru_kernel(
    const float* __restrict__ x,      // [128, 256]
    const float* __restrict__ w_ih,   // [1536, 256]
    const float* __restrict__ w_hh,   // [1536, 512] fp32 (converted here)
    const float* __restrict__ b_ih,   // [1536]
    const float* __restrict__ b_hh,   // [1536]
    unsigned* __restrict__ hbuf_u32,  // 2 * [128, 512] bf16, dword-addressed
    unsigned* __restrict__ flags,     // [BG*HG]
    float* __restrict__ out)          // [128, 1024, 512] fp32
{
    const int lane = threadIdx.x;
    const int bg = blockIdx.x & 7;
    const int hg = blockIdx.x >> 3;
    const int b0 = bg * ROWS;
    const int c0 = hg * 16;
    const int nlo = lane & 15;
    const int quad = lane >> 4;

    // w_hh/gi rows for this lane's three gate tiles
    int gcol[NT];
    gcol[0] = c0 + nlo;           // r
    gcol[1] = HD + c0 + nlo;      // z
    gcol[2] = 2 * HD + c0 + nlo;  // n

    // ---- stage w_hh slice -> LDS in fragment order (once) ----
    // ldsB[(t*16+kc)*64 + lane] = whh[gcol_t(nlo)][kc*32 + quad*8 .. +8] (bf16)
    __shared__ frag16 ldsB[NT * 16 * 64];  // 48 KB
#pragma unroll
    for (int t = 0; t < NT; ++t) {
        for (int kc = 0; kc < 16; ++kc) {
            const float* src = w_hh + (size_t)gcol[t] * HD + kc * 32 + quad * 8;
            float4 v0 = *(const float4*)src;
            float4 v1 = *(const float4*)(src + 4);
            frag16 f;
            f[0] = f2bf(v0.x); f[1] = f2bf(v0.y); f[2] = f2bf(v0.z); f[3] = f2bf(v0.w);
            f[4] = f2bf(v1.x); f[5] = f2bf(v1.y); f[6] = f2bf(v1.z); f[7] = f2bf(v1.w);
            ldsB[(t * 16 + kc) * 64 + lane] = f;
        }
    }

    // ---- gi = x @ w_ih.T + b_ih (+ b_hh folded for r,z) ----
    float gi[NT][4];
    float bhn = b_hh[gcol[2]];
#pragma unroll
    for (int t = 0; t < NT; ++t) {
        float bi = b_ih[gcol[t]] + ((t < 2) ? b_hh[gcol[t]] : 0.f);
#pragma unroll
        for (int r = 0; r < 4; ++r) gi[t][r] = bi;
    }
    for (int r = 0; r < 4; ++r) {
        const float4* xr = (const float4*)(x + (size_t)(b0 + quad * 4 + r) * IND);
        for (int kc = 0; kc < IND / 4; ++kc) {
            float4 xv = xr[kc];
#pragma unroll
            for (int t = 0; t < NT; ++t) {
                float4 wv = ((const float4*)(w_ih + (size_t)gcol[t] * IND))[kc];
                gi[t][r] += xv.x * wv.x + xv.y * wv.y + xv.z * wv.z + xv.w * wv.w;
            }
        }
    }

    // ---- recurrence ----
    const int HWORDS = BATCH * HD / 2;  // dwords per h buffer
    const uint64_t a_dw = ((uint64_t)(b0 + nlo) * HD + quad * 8) >> 1;

    float hreg[4];
#pragma unroll
    for (int r = 0; r < 4; ++r) hreg[r] = 0.f;

    unsigned* myflag = flags + bg * HG + hg;
    unsigned* pollflag = flags + bg * HG + (lane & 31);

    for (int s = 0; s < SEQ; ++s) {
        f32x4 C[NT];
#pragma unroll
        for (int t = 0; t < NT; ++t) C[t] = (f32x4){0.f, 0.f, 0.f, 0.f};

        if (s > 0) {
            unsigned long long* hb =
                (unsigned long long*)(hbuf_u32 + (s & 1) * HWORDS);
            unsigned long long a0[16], a1[16];
#pragma unroll
            for (int kc = 0; kc < 16; ++kc) {
                unsigned long long* p = hb + ((a_dw + kc * 16) >> 1);
                a0[kc] = __hip_atomic_load(p,     __ATOMIC_RELAXED, __HIP_MEMORY_SCOPE_SYSTEM);
                a1[kc] = __hip_atomic_load(p + 1, __ATOMIC_RELAXED, __HIP_MEMORY_SCOPE_SYSTEM);
            }
#pragma unroll
            for (int kc = 0; kc < 16; ++kc) {
                union { unsigned long long u[2]; frag16 f; } af;
                af.u[0] = a0[kc];
                af.u[1] = a1[kc];
#pragma unroll
                for (int t = 0; t < NT; ++t) {
                    frag16 bfr = ldsB[(t * 16 + kc) * 64 + lane];
                    C[t] = __builtin_amdgcn_mfma_f32_16x16x32_bf16(af.f, bfr, C[t], 0, 0, 0);
                }
            }
        }

        unsigned* hw = hbuf_u32 + ((s + 1) & 1) * HWORDS;
#pragma unroll
        for (int r = 0; r < 4; ++r) {
            float gr  = gi[0][r] + C[0][r];
            float gz  = gi[1][r] + C[1][r];
            float ghn = C[2][r] + bhn;
            float rr = sigmoid_f(gr);
            float zz = sigmoid_f(gz);
            float nn = tanh_f(gi[2][r] + rr * ghn);
            float hn = (1.f - zz) * nn + zz * hreg[r];
            hreg[r] = hn;
            int row = b0 + quad * 4 + r;
            int col = c0 + nlo;
            out[(uint64_t)row * (SEQ * HD) + (uint64_t)s * HD + col] = hn;
            // bf16 exchange: pack adjacent-col pair across lane^1, even lane stores dword
            unsigned own = (unsigned)(unsigned short)f2bf(hn);
            unsigned other = (unsigned)__shfl_xor((int)own, 1);
            if ((lane & 1) == 0) {
                unsigned dw = own | (other << 16);
                __hip_atomic_store(hw + ((unsigned)(row * HD + col) >> 1), dw,
                                   __ATOMIC_RELAXED, __HIP_MEMORY_SCOPE_SYSTEM);
            }
        }

        if (s < SEQ - 1) {
            // drain h stores to the coherence point, then publish (compiler barrier too)
            asm volatile("s_waitcnt vmcnt(0)" ::: "memory");
            if (lane == 0)
                __hip_atomic_store(myflag, (unsigned)(s + 1),
                                   __ATOMIC_RELAXED, __HIP_MEMORY_SCOPE_SYSTEM);
            // relaxed poll: all 32 producer flags of this batch group >= s+1
            bool done = false;
            do {
                unsigned v = __hip_atomic_load(pollflag, __ATOMIC_RELAXED,
                                               __HIP_MEMORY_SCOPE_SYSTEM);
                done = (__ballot(v > (unsigned)s) == ~0ull);
            } while (!done);
            asm volatile("" ::: "memory");  // no hoisting next-step loads above poll
        }
    }
}

extern "C" void kernel_launch(void* const* d_in, const int* in_sizes, int n_in,
                              void* d_out, int out_size, void* d_ws, size_t ws_size,
                              hipStream_t stream) {
    (void)in_sizes; (void)n_in; (void)out_size; (void)ws_size;
    const float* x    = (const float*)d_in[0];
    const float* w_ih = (const float*)d_in[1];
    const float* w_hh = (const float*)d_in[2];
    const float* b_ih = (const float*)d_in[3];
    const float* b_hh = (const float*)d_in[4];

    char* ws = (char*)d_ws;
    unsigned* hbuf  = (unsigned*)(ws + WS_HBUF);
    unsigned* flags = (unsigned*)(ws + WS_FLAGS);

    hipMemsetAsync(flags, 0, (size_t)BG * HG * sizeof(unsigned), stream);
    gru_kernel<<<BG * HG, 64, 0, stream>>>(x, w_ih, w_hh, b_ih, b_hh, hbuf, flags,
                                           (float*)d_out);
}